// Round 3
// baseline (185.074 us; speedup 1.0000x reference)
//
#include <hip/hip_runtime.h>
#include <math.h>

#define B 8
#define C 64
#define HIN 224
#define WIN 224
#define PLANE (HIN*WIN)        // 50176
#define PLANE4 (PLANE/4)       // 12544
#define QUART (PLANE4/4)       // 3136
#define OH 64
#define OW 128
#define OUT_PER_BC (OH*OW)     // 8192
#define POOLED_SIZE (B*C*OH*OW) // 4194304

// ws layout (floats): [0, 2048) partial sums [bc][quarter]
#define WS_PARTIAL 0

#define PI_F 3.14159265358979323846f

__device__ __forceinline__ float bilinear(const float* __restrict__ p,
                                          float ix, float iy) {
    float x0f = floorf(ix), y0f = floorf(iy);
    int x0 = (int)x0f, y0 = (int)y0f;
    float wx = ix - x0f, wy = iy - y0f;
    int x1 = min(x0 + 1, WIN - 1);
    int y1 = min(y0 + 1, HIN - 1);
    const float* r0 = p + y0 * WIN;
    const float* r1 = p + y1 * WIN;
    float v00 = r0[x0], v01 = r0[x1], v10 = r1[x0], v11 = r1[x1];
    float v0 = v00 + (v01 - v00) * wx;
    float v1 = v10 + (v11 - v10) * wx;
    return v0 + (v1 - v0) * wy;
}

// ---------------- K1: gap partial sums + constant-region fill ----------------
__global__ __launch_bounds__(256) void k1_gap_fill(const float* __restrict__ x,
                                                   const float* __restrict__ l_t,
                                                   float* __restrict__ ws,
                                                   float* __restrict__ out) {
    int blk = blockIdx.x;          // bc*4 + q
    int bc  = blk >> 2, q = blk & 3;
    int b   = bc >> 6;
    int tid = threadIdx.x;

    const float4* p = (const float4*)x + (size_t)bc * PLANE4 + q * QUART;
    float s = 0.f;
#pragma unroll
    for (int k = 0; k < 12; ++k) {
        float4 v = p[tid + k * 256];
        s += (v.x + v.y) + (v.z + v.w);
    }
    if (tid < QUART - 12 * 256) {  // remainder: 64 float4s
        float4 v = p[tid + 12 * 256];
        s += (v.x + v.y) + (v.z + v.w);
    }

    // Constant-region: grid == (0,0) + l_t_prev[b] outside the 64x128 fine
    // corner -> after 4x4 pooling, all outputs with h>=16 or w>=32 equal ONE
    // bilinear sample.
    const float* plane = x + (size_t)bc * PLANE;
    float gx = l_t[b * 2 + 0], gy = l_t[b * 2 + 1];
    float ixc = fminf(fmaxf(((gx + 1.f) * (float)WIN - 1.f) * 0.5f, 0.f), (float)(WIN - 1));
    float iyc = fminf(fmaxf(((gy + 1.f) * (float)HIN - 1.f) * 0.5f, 0.f), (float)(HIN - 1));
    float vc = bilinear(plane, ixc, iyc);   // uniform addresses across wave: 1 txn
    float4 vc4 = make_float4(vc, vc, vc, vc);

    float4* o4 = (float4*)(out + (size_t)bc * OUT_PER_BC);
    if (q == 0) {
        // rows h=0..15; const part is w in [32,128) -> f4 cols 8..31
#pragma unroll
        for (int k = 0; k < 2; ++k) {
            int f4i = tid + k * 256;
            if (f4i < 384) {
                int row = f4i / 24;
                int c4  = f4i - row * 24 + 8;
                o4[row * 32 + c4] = vc4;
            }
        }
    } else {
        // h>=16, fully constant. 512 float4s.
        o4[q * 512 + tid]       = vc4;
        o4[q * 512 + 256 + tid] = vc4;
    }

    // wave (64-lane) reduce, then cross-wave via LDS
    for (int off = 32; off; off >>= 1) s += __shfl_down(s, off, 64);
    __shared__ float lds[4];
    if ((tid & 63) == 0) lds[tid >> 6] = s;
    __syncthreads();
    if (tid == 0) ws[WS_PARTIAL + blk] = lds[0] + lds[1] + lds[2] + lds[3];
}

// ---------------- K3: fused MLP + coords + bilinear sample + 4x4 pool -------
// The old k2 dispatch was ~0.15 us of math inside a ~4-6 us whole-GPU launch.
// Each block now recomputes its batch's tiny MLP (2048 MACs, once, into LDS)
// and each thread computes its own 2 sampling coords inline — the 64x
// redundant transcendental work hides under gather latency.
// Wave-tiled gather (round-2 layout, verified): each wave owns a contiguous
// 8x16 fine patch; 2 samples/thread; 4x4 pooling via shfl_xor tree.
__global__ __launch_bounds__(256) void k3_fused(const float* __restrict__ x,
                                                const float* __restrict__ w1,
                                                const float* __restrict__ b1,
                                                const float* __restrict__ w2,
                                                const float* __restrict__ b2,
                                                const float* __restrict__ l_t,
                                                const float* __restrict__ ws,
                                                float* __restrict__ out_weight,
                                                float* __restrict__ out) {
    int blk   = blockIdx.x;        // 0..8191 = bc*16 + patch
    int bc    = blk >> 4;
    int patch = blk & 15;
    int b     = bc >> 6;
    int tid   = threadIdx.x;

    __shared__ float branch[C];
    __shared__ float hidden[32];
    __shared__ float sparams[4];   // lo, hi, ltx, lty

    if (tid < C) {
        const float* pp = ws + WS_PARTIAL + (b * C + tid) * 4;
        branch[tid] = (pp[0] + pp[1] + pp[2] + pp[3]) * (1.0f / PLANE);
    }
    __syncthreads();
    if (tid < 32) {
        float h = b1[tid];
        for (int c = 0; c < C; ++c) h += branch[c] * w1[c * 32 + tid];
        hidden[tid] = h > 0.f ? h : 0.f;
    }
    __syncthreads();
    if (tid < 2) {
        float sacc = b2[tid];
        for (int m = 0; m < 32; ++m) sacc += hidden[m] * w2[m * 2 + tid];
        float wv = 1.f / (1.f + expf(-sacc));
        if ((bc & 63) == 0 && patch == 0) out_weight[b * 2 + tid] = wv;
        // lo = log(w0*R_MIN), hi = log(w1*R_MAX)
        sparams[tid]     = logf(wv * (tid == 0 ? 0.01f : 0.6f));
        sparams[2 + tid] = l_t[b * 2 + tid];
    }
    __syncthreads();

    float lo  = sparams[0], hi = sparams[1];
    float inv_hl = 1.f / (hi - lo);
    float ltx = sparams[2], lty = sparams[3];

    int wave   = tid >> 6;         // 0..3
    int lane   = tid & 63;
    int wave_h = wave >> 1;        // 0..1
    int wave_w = wave & 1;         // 0..1
    int fi_l   = lane >> 3;        // 0..7
    int fj_l   = lane & 7;         // 0..7

    int pb_h = patch >> 2;         // 0..3
    int pb_w = patch & 3;          // 0..3
    int fi   = pb_h * 16 + wave_h * 8 + fi_l;         // fine row 0..63
    int fjb  = pb_w * 32 + wave_w * 16;               // fine col base
    int fj0  = fjb + fj_l;
    int fj1  = fjb + 8 + fj_l;

    // inline coords (both samples share fi -> shared xg)
    float xg = (float)(fi - 32) * (1.f / 32.f);
    float ix0, iy0, ix1, iy1;
    {
        float yg = (float)(fj0 - 64) * (1.f / 64.f);
        float rr = sqrtf(xg * xg + yg * yg);
        float r  = 64.f * (logf(fmaxf(rr, 1e-12f)) - lo) * inv_hl;
        float a  = atan2f(yg, xg);
        if (!(a > 0.f)) a = 2.f * PI_F + a;
        float t  = a * (32.f / PI_F);
        float gxv = t * (1.f / 32.f) - 1.f + ltx;
        float gyv = r * (1.f / 32.f) - 1.f + lty;
        ix0 = fminf(fmaxf(((gxv + 1.f) * (float)WIN - 1.f) * 0.5f, 0.f), (float)(WIN - 1));
        iy0 = fminf(fmaxf(((gyv + 1.f) * (float)HIN - 1.f) * 0.5f, 0.f), (float)(HIN - 1));
    }
    {
        float yg = (float)(fj1 - 64) * (1.f / 64.f);
        float rr = sqrtf(xg * xg + yg * yg);
        float r  = 64.f * (logf(fmaxf(rr, 1e-12f)) - lo) * inv_hl;
        float a  = atan2f(yg, xg);
        if (!(a > 0.f)) a = 2.f * PI_F + a;
        float t  = a * (32.f / PI_F);
        float gxv = t * (1.f / 32.f) - 1.f + ltx;
        float gyv = r * (1.f / 32.f) - 1.f + lty;
        ix1 = fminf(fmaxf(((gxv + 1.f) * (float)WIN - 1.f) * 0.5f, 0.f), (float)(WIN - 1));
        iy1 = fminf(fmaxf(((gyv + 1.f) * (float)HIN - 1.f) * 0.5f, 0.f), (float)(HIN - 1));
    }

    const float* plane = x + (size_t)bc * PLANE;
    float a0 = bilinear(plane, ix0, iy0);
    float a1 = bilinear(plane, ix1, iy1);

    // pool 4x4: reduce over fj_l bits (lanes 1,2) and fi_l bits (lanes 8,16)
    a0 += __shfl_xor(a0, 1, 64);  a1 += __shfl_xor(a1, 1, 64);
    a0 += __shfl_xor(a0, 2, 64);  a1 += __shfl_xor(a1, 2, 64);
    a0 += __shfl_xor(a0, 8, 64);  a1 += __shfl_xor(a1, 8, 64);
    a0 += __shfl_xor(a0, 16, 64); a1 += __shfl_xor(a1, 16, 64);

    if ((lane & 27) == 0) {        // fi_l%4==0 && fj_l%4==0: lanes 0,4,32,36
        int ph = pb_h * 4 + wave_h * 2 + (fi_l >> 2);
        int pw = pb_w * 8 + wave_w * 4 + (fj_l >> 2);
        float* o = out + (size_t)bc * OUT_PER_BC + ph * 128 + pw;
        o[0] = a0 * (1.f / 16.f);
        o[2] = a1 * (1.f / 16.f);
    }
}

extern "C" void kernel_launch(void* const* d_in, const int* in_sizes, int n_in,
                              void* d_out, int out_size, void* d_ws, size_t ws_size,
                              hipStream_t stream) {
    const float* x   = (const float*)d_in[0];
    const float* l_t = (const float*)d_in[1];
    const float* w1  = (const float*)d_in[2];
    const float* b1  = (const float*)d_in[3];
    const float* w2  = (const float*)d_in[4];
    const float* b2  = (const float*)d_in[5];
    float* out = (float*)d_out;
    float* ws  = (float*)d_ws;

    k1_gap_fill<<<dim3(B * C * 4), dim3(256), 0, stream>>>(x, l_t, ws, out);
    k3_fused<<<dim3(B * C * 16), dim3(256), 0, stream>>>(
        x, w1, b1, w2, b2, l_t, ws, out + POOLED_SIZE, out);
}